// Round 2
// baseline (476.800 us; speedup 1.0000x reference)
//
#include <hip/hip_runtime.h>

// Problem constants: B=2, S=2048, D=1024, H=16, HD=64
#define S_LEN 2048
#define NH 16
#define HD 64
#define DMODEL 1024

typedef __bf16 bf16x8 __attribute__((ext_vector_type(8)));
typedef float floatx4 __attribute__((ext_vector_type(4)));
typedef short short8 __attribute__((ext_vector_type(8)));
typedef short short4v __attribute__((ext_vector_type(4)));

__device__ inline unsigned short f2bf(float f) {
    union { float f; unsigned u; } v; v.f = f;
    unsigned u = v.u;
    unsigned r = (u + 0x7FFFu + ((u >> 16) & 1u)) >> 16;  // RNE
    return (unsigned short)r;
}

__device__ __forceinline__ void gload_lds16(const void* g, void* l) {
    __builtin_amdgcn_global_load_lds(
        (const __attribute__((address_space(1))) unsigned int*)g,
        (__attribute__((address_space(3))) unsigned int*)l, 16, 0, 0);
}

// ---------------------------------------------------------------------------
// K1: qkv = x @ w_qkv^T + b_qkv, fused RoPE, scatter to q/k/v (B,H,S,HD) bf16
// ---------------------------------------------------------------------------
__global__ __launch_bounds__(256) void qkv_rope_kernel(
    const float* __restrict__ x, const float* __restrict__ w,
    const float* __restrict__ bias, const float* __restrict__ freqs,
    unsigned short* __restrict__ qb, unsigned short* __restrict__ kb,
    unsigned short* __restrict__ vb)
{
    __shared__ __align__(16) unsigned short As[64 * 40];
    __shared__ __align__(16) unsigned short Bs[64 * 40];
    const int t = threadIdx.x;
    const int mbase = (blockIdx.x / 48) * 64;
    const int nbase = (blockIdx.x % 48) * 64;
    const int wv = t >> 6, lane = t & 63;
    const int quad = lane >> 4, l16 = lane & 15;

    floatx4 acc[4];
    for (int i = 0; i < 4; i++)
        for (int r = 0; r < 4; r++) acc[i][r] = 0.f;

    const int srow = t >> 2;
    const int sc8  = (t & 3) * 8;

    for (int k0 = 0; k0 < DMODEL; k0 += 32) {
        const float* ap = x + (size_t)(mbase + srow) * DMODEL + k0 + sc8;
        const float* bp = w + (size_t)(nbase + srow) * DMODEL + k0 + sc8;
        float4 a0 = *(const float4*)ap;
        float4 a1 = *(const float4*)(ap + 4);
        float4 b0 = *(const float4*)bp;
        float4 b1 = *(const float4*)(bp + 4);
        short8 av, bv;
        av[0]=(short)f2bf(a0.x); av[1]=(short)f2bf(a0.y); av[2]=(short)f2bf(a0.z); av[3]=(short)f2bf(a0.w);
        av[4]=(short)f2bf(a1.x); av[5]=(short)f2bf(a1.y); av[6]=(short)f2bf(a1.z); av[7]=(short)f2bf(a1.w);
        bv[0]=(short)f2bf(b0.x); bv[1]=(short)f2bf(b0.y); bv[2]=(short)f2bf(b0.z); bv[3]=(short)f2bf(b0.w);
        bv[4]=(short)f2bf(b1.x); bv[5]=(short)f2bf(b1.y); bv[6]=(short)f2bf(b1.z); bv[7]=(short)f2bf(b1.w);
        __syncthreads();
        *(short8*)&As[srow * 40 + sc8] = av;
        *(short8*)&Bs[srow * 40 + sc8] = bv;
        __syncthreads();
        bf16x8 af = *(const bf16x8*)&As[(wv * 16 + l16) * 40 + quad * 8];
        for (int nt = 0; nt < 4; nt++) {
            bf16x8 bf = *(const bf16x8*)&Bs[(nt * 16 + l16) * 40 + quad * 8];
            acc[nt] = __builtin_amdgcn_mfma_f32_16x16x32_bf16(af, bf, acc[nt], 0, 0, 0);
        }
    }

    for (int nt = 0; nt < 4; nt++) {
        const int n = nbase + nt * 16 + l16;
        const int part = n >> 10;
        const int rem  = n & 1023;
        const int h    = rem >> 6;
        const int hd   = rem & 63;
        unsigned short* dst = (part == 0) ? qb : (part == 1) ? kb : vb;
        const float bvv = bias[n];
        for (int r = 0; r < 4; r++) {
            const int m = mbase + wv * 16 + quad * 4 + r;
            const int b = m >> 11;
            const int s = m & 2047;
            float val = acc[nt][r] + bvv;
            float other = __shfl_xor(val, 1, 64);
            float outv;
            if (part == 2) {
                outv = val;
            } else {
                const int i = hd >> 1;
                const float f = freqs[s * 32 + i];
                const float c = cosf(f), sn = sinf(f);
                if ((hd & 1) == 0) outv = val * c - other * sn;
                else               outv = other * sn + val * c;
            }
            dst[(((size_t)b * NH + h) * S_LEN + s) * HD + hd] = f2bf(outv);
        }
    }
}

// ---------------------------------------------------------------------------
// K2: causal flash attention, paired q-tiles for uniform work.
// Block = 256 thr (4 waves). Each block: q-tiles {p, 31-p} (64 rows each),
// shared K/V staging, 64-key tiles. Grid = 16 pairs * 32 bh = 512 blocks.
//   K staged via global_load_lds into block-interleaved layout:
//     Ks element (key,d) at short offset (d>>3)*512 + key*8 + (d&7)
//   V transposed via paired-uint writes (conflict-free), stride 68.
// ---------------------------------------------------------------------------
__global__ __launch_bounds__(256, 2) void attn_kernel(
    const unsigned short* __restrict__ qb, const unsigned short* __restrict__ kb,
    const unsigned short* __restrict__ vb, unsigned short* __restrict__ ao)
{
    __shared__ __align__(16) unsigned short Ks[8 * 512];     // 8 KB
    __shared__ __align__(16) unsigned short Vt[64 * 68];     // 8.5 KB, [hd][key]
    __shared__ __align__(16) unsigned short Pw[4][16 * 72];  // 9 KB, per-wave

    const int t = threadIdx.x;
    const int wv = t >> 6, lane = t & 63, quad = lane >> 4, l16 = lane & 15;
    const int p  = blockIdx.x >> 5;        // 0..15
    const int bh = blockIdx.x & 31;
    const int h = bh & 15, b = bh >> 4;
    const int qt0 = p, qt1 = 31 - p;       // lo / hi q-tiles
    const size_t base = ((size_t)b * NH + h) * S_LEN * HD;
    const unsigned short* qg = qb + base;
    const unsigned short* kg = kb + base;
    const unsigned short* vg = vb + base;

    bf16x8 qf[2][2];
    {
        const unsigned short* q0 = qg + (size_t)(qt0 * 64 + wv * 16 + l16) * HD;
        const unsigned short* q1 = qg + (size_t)(qt1 * 64 + wv * 16 + l16) * HD;
        qf[0][0] = *(const bf16x8*)&q0[quad * 8];
        qf[0][1] = *(const bf16x8*)&q0[32 + quad * 8];
        qf[1][0] = *(const bf16x8*)&q1[quad * 8];
        qf[1][1] = *(const bf16x8*)&q1[32 + quad * 8];
    }

    float mrow[2][4], lrow[2][4];
    floatx4 Ofr[2][4];
    for (int ti = 0; ti < 2; ti++)
        for (int r = 0; r < 4; r++) { mrow[ti][r] = -1e30f; lrow[ti][r] = 0.f; }
    for (int ti = 0; ti < 2; ti++)
        for (int nt = 0; nt < 4; nt++)
            for (int r = 0; r < 4; r++) Ofr[ti][nt][r] = 0.f;

    const int vk2 = t & 31, vhd0 = (t >> 5) << 3;
    const int ntiles = qt1 + 1;

    for (int kt = 0; kt < ntiles; kt++) {
        const int kbase = kt * 64;
        // --- K staging: async direct-to-LDS, wave wv fills hd-blocks 2wv,2wv+1
        {
            const unsigned short* g0 = kg + (size_t)(kbase + lane) * HD + (wv * 2) * 8;
            gload_lds16(g0, &Ks[(wv * 2) * 512]);
            gload_lds16(g0 + 8, &Ks[(wv * 2 + 1) * 512]);
        }
        // --- V staging: key-pair packed transpose (bank-conflict-free)
        {
            const unsigned short* v0 = vg + (size_t)(kbase + vk2 * 2) * HD + vhd0;
            short8 va  = *(const short8*)v0;
            short8 vb8 = *(const short8*)(v0 + HD);
            #pragma unroll
            for (int j = 0; j < 8; j++) {
                unsigned int pk = (unsigned int)(unsigned short)va[j] |
                                  ((unsigned int)(unsigned short)vb8[j] << 16);
                *(unsigned int*)&Vt[(vhd0 + j) * 68 + vk2 * 2] = pk;
            }
        }
        __syncthreads();

        // K fragments, shared by both q-tiles
        bf16x8 kf[4][2];
        #pragma unroll
        for (int sub = 0; sub < 4; sub++)
            #pragma unroll
            for (int hc = 0; hc < 2; hc++)
                kf[sub][hc] = *(const bf16x8*)&Ks[(hc * 4 + quad) * 512 + (sub * 16 + l16) * 8];

        const int ndo = (kt <= p) ? 2 : 1;
        for (int tii = 0; tii < ndo; tii++) {
            const int ti = (tii == 0) ? 1 : 0;   // hi tile always; lo if kt<=p
            const int qt = ti ? qt1 : qt0;

            float pex[4][4];
            #pragma unroll
            for (int sub = 0; sub < 4; sub++) {
                floatx4 sacc = {0.f, 0.f, 0.f, 0.f};
                sacc = __builtin_amdgcn_mfma_f32_16x16x32_bf16(qf[ti][0], kf[sub][0], sacc, 0, 0, 0);
                sacc = __builtin_amdgcn_mfma_f32_16x16x32_bf16(qf[ti][1], kf[sub][1], sacc, 0, 0, 0);
                #pragma unroll
                for (int r = 0; r < 4; r++) pex[sub][r] = sacc[r] * 0.125f;
            }
            if (kt == qt) {   // diagonal tile: causal mask
                #pragma unroll
                for (int sub = 0; sub < 4; sub++) {
                    const int key = kbase + sub * 16 + l16;
                    #pragma unroll
                    for (int r = 0; r < 4; r++) {
                        const int qr = qt * 64 + wv * 16 + quad * 4 + r;
                        if (key > qr) pex[sub][r] = -3e38f;
                    }
                }
            }
            // online softmax (row = quad*4+r, 16 cols across l16)
            #pragma unroll
            for (int r = 0; r < 4; r++) {
                float mx = fmaxf(fmaxf(pex[0][r], pex[1][r]), fmaxf(pex[2][r], pex[3][r]));
                for (int off = 1; off < 16; off <<= 1) mx = fmaxf(mx, __shfl_xor(mx, off, 64));
                const float mnew = fmaxf(mrow[ti][r], mx);
                const float alpha = __expf(mrow[ti][r] - mnew);
                mrow[ti][r] = mnew;
                float rs = 0.f;
                #pragma unroll
                for (int sub = 0; sub < 4; sub++) {
                    pex[sub][r] = __expf(pex[sub][r] - mnew);
                    rs += pex[sub][r];
                }
                for (int off = 1; off < 16; off <<= 1) rs += __shfl_xor(rs, off, 64);
                lrow[ti][r] = lrow[ti][r] * alpha + rs;
                #pragma unroll
                for (int nt = 0; nt < 4; nt++) Ofr[ti][nt][r] *= alpha;
            }
            // P: C-layout -> LDS -> A-layout
            #pragma unroll
            for (int sub = 0; sub < 4; sub++)
                #pragma unroll
                for (int r = 0; r < 4; r++)
                    Pw[wv][(quad * 4 + r) * 72 + sub * 16 + l16] = f2bf(pex[sub][r]);
            __syncthreads();
            bf16x8 pf[2];
            pf[0] = *(const bf16x8*)&Pw[wv][l16 * 72 + quad * 8];
            pf[1] = *(const bf16x8*)&Pw[wv][l16 * 72 + 32 + quad * 8];
            // PV accumulate
            #pragma unroll
            for (int nt = 0; nt < 4; nt++) {
                #pragma unroll
                for (int kc = 0; kc < 2; kc++) {
                    const unsigned short* vp = &Vt[(nt * 16 + l16) * 68 + kc * 32 + quad * 8];
                    union { struct { short4v a, bq; } s; bf16x8 v; } u;
                    u.s.a  = *(const short4v*)vp;
                    u.s.bq = *(const short4v*)(vp + 4);
                    Ofr[ti][nt] = __builtin_amdgcn_mfma_f32_16x16x32_bf16(pf[kc], u.v, Ofr[ti][nt], 0, 0, 0);
                }
            }
        }
        __syncthreads();   // protect Ks/Vt before next tile's staging
    }

    #pragma unroll
    for (int ti = 0; ti < 2; ti++) {
        const int qt = ti ? qt1 : qt0;
        float inv[4];
        for (int r = 0; r < 4; r++) inv[r] = 1.f / lrow[ti][r];
        for (int nt = 0; nt < 4; nt++)
            for (int r = 0; r < 4; r++) {
                const int s = qt * 64 + wv * 16 + quad * 4 + r;
                ao[((size_t)b * S_LEN + s) * DMODEL + h * HD + nt * 16 + l16] =
                    f2bf(Ofr[ti][nt][r] * inv[r]);
            }
    }
}

// ---------------------------------------------------------------------------
// K3: out = ao @ w_proj^T + b_proj.  M=4096, N=1024, K=1024. fp32 out.
// ---------------------------------------------------------------------------
__global__ __launch_bounds__(256) void proj_kernel(
    const unsigned short* __restrict__ a, const float* __restrict__ w,
    const float* __restrict__ bias, float* __restrict__ out)
{
    __shared__ __align__(16) unsigned short As[64 * 40];
    __shared__ __align__(16) unsigned short Bs[64 * 40];
    const int t = threadIdx.x;
    const int mbase = (blockIdx.x >> 4) * 64;
    const int nbase = (blockIdx.x & 15) * 64;
    const int wv = t >> 6, lane = t & 63, quad = lane >> 4, l16 = lane & 15;

    floatx4 acc[4];
    for (int i = 0; i < 4; i++)
        for (int r = 0; r < 4; r++) acc[i][r] = 0.f;

    const int srow = t >> 2, sc8 = (t & 3) * 8;

    for (int k0 = 0; k0 < DMODEL; k0 += 32) {
        short8 av = *(const short8*)&a[(size_t)(mbase + srow) * DMODEL + k0 + sc8];
        const float* bp = w + (size_t)(nbase + srow) * DMODEL + k0 + sc8;
        float4 b0 = *(const float4*)bp;
        float4 b1 = *(const float4*)(bp + 4);
        short8 bv;
        bv[0]=(short)f2bf(b0.x); bv[1]=(short)f2bf(b0.y); bv[2]=(short)f2bf(b0.z); bv[3]=(short)f2bf(b0.w);
        bv[4]=(short)f2bf(b1.x); bv[5]=(short)f2bf(b1.y); bv[6]=(short)f2bf(b1.z); bv[7]=(short)f2bf(b1.w);
        __syncthreads();
        *(short8*)&As[srow * 40 + sc8] = av;
        *(short8*)&Bs[srow * 40 + sc8] = bv;
        __syncthreads();
        bf16x8 af = *(const bf16x8*)&As[(wv * 16 + l16) * 40 + quad * 8];
        for (int nt = 0; nt < 4; nt++) {
            bf16x8 bf = *(const bf16x8*)&Bs[(nt * 16 + l16) * 40 + quad * 8];
            acc[nt] = __builtin_amdgcn_mfma_f32_16x16x32_bf16(af, bf, acc[nt], 0, 0, 0);
        }
    }

    for (int nt = 0; nt < 4; nt++) {
        const int n = nbase + nt * 16 + l16;
        const float bvv = bias[n];
        for (int r = 0; r < 4; r++) {
            const int m = mbase + wv * 16 + quad * 4 + r;
            out[(size_t)m * DMODEL + n] = acc[nt][r] + bvv;
        }
    }
}

extern "C" void kernel_launch(void* const* d_in, const int* in_sizes, int n_in,
                              void* d_out, int out_size, void* d_ws, size_t ws_size,
                              hipStream_t stream) {
    const float* x      = (const float*)d_in[0];
    const float* freqs  = (const float*)d_in[2];
    const float* w_qkv  = (const float*)d_in[3];
    const float* b_qkv  = (const float*)d_in[4];
    const float* w_proj = (const float*)d_in[5];
    const float* b_proj = (const float*)d_in[6];
    float* out = (float*)d_out;

    unsigned short* ws = (unsigned short*)d_ws;
    const size_t HSZ = (size_t)2 * NH * S_LEN * HD;
    unsigned short* qb = ws;
    unsigned short* kb = ws + HSZ;
    unsigned short* vb = ws + 2 * HSZ;
    unsigned short* ao = ws + 3 * HSZ;

    qkv_rope_kernel<<<3072, 256, 0, stream>>>(x, w_qkv, b_qkv, freqs, qb, kb, vb);
    attn_kernel<<<512, 256, 0, stream>>>(qb, kb, vb, ao);
    proj_kernel<<<1024, 256, 0, stream>>>(ao, w_proj, b_proj, out);
}